// Round 2
// baseline (291.417 us; speedup 1.0000x reference)
//
#include <hip/hip_runtime.h>

#define NBATCH 128
#define NPB    262144      // 1*512*512 elements per batch
#define BINS   256

// ---------------------------------------------------------------- zero hist
__global__ __launch_bounds__(256) void zero_hist(unsigned int* __restrict__ h) {
    h[blockIdx.x * 256 + threadIdx.x] = 0u;   // grid 128 -> 32768 uints
}

// ---------------------------------------------------------------- histogram
// 32 blocks per batch, 8192 elems per block (256 thr * 8 float4-quarters).
__global__ __launch_bounds__(256) void hist_kernel(const float* __restrict__ x,
                                                   unsigned int* __restrict__ gh) {
    __shared__ unsigned int lh[4][BINS];   // per-wave sub-histograms
    const int tid = threadIdx.x;
    const int wid = tid >> 6;
    for (int i = tid; i < 4 * BINS; i += 256) ((unsigned int*)lh)[i] = 0u;
    __syncthreads();

    const int batch = blockIdx.x >> 5;
    const int chunk = blockIdx.x & 31;
    const float4* xp = (const float4*)(x + (size_t)batch * NPB + (size_t)chunk * 8192);
    unsigned int* mh = lh[wid];

    #pragma unroll
    for (int it = 0; it < 8; ++it) {
        float4 v = xp[it * 256 + tid];
        float vals[4] = {v.x, v.y, v.z, v.w};
        #pragma unroll
        for (int j = 0; j < 4; ++j) {
            float f = vals[j];
            // exact replica of jnp: clip(floor(f*256), 0, 255); ignore out-of-[0,1]
            int bin = (int)floorf(f * 256.0f);
            bin = bin < 0 ? 0 : (bin > 255 ? 255 : bin);
            if (f >= 0.0f && f <= 1.0f) atomicAdd(&mh[bin], 1u);
        }
    }
    __syncthreads();
    unsigned int s = lh[0][tid] + lh[1][tid] + lh[2][tid] + lh[3][tid];
    if (s) atomicAdd(&gh[batch * BINS + tid], s);
}

// ---------------------------------------------------------------- mlp+value
__global__ __launch_bounds__(256) void mlp_kernel(const unsigned int* __restrict__ gh,
    const float* __restrict__ W1, const float* __restrict__ b1,
    const float* __restrict__ W2, const float* __restrict__ b2,
    const float* __restrict__ W3, const float* __restrict__ b3,
    const float* __restrict__ W4, const float* __restrict__ b4,
    float* __restrict__ wout, float* __restrict__ value_out) {

    __shared__ float sh[BINS];
    __shared__ float sval[BINS];
    __shared__ int   sidx[BINS];
    __shared__ float h1[32], h2[64], h3[128];

    const int tid = threadIdx.x;
    const int b   = blockIdx.x;

    float hv = (float)gh[b * BINS + tid];
    sh[tid]   = hv;
    sval[tid] = hv;
    sidx[tid] = tid;
    __syncthreads();

    // max + FIRST argmax (jnp.argmax tie-break: lowest index)
    for (int off = 128; off > 0; off >>= 1) {
        if (tid < off) {
            float vr = sval[tid + off]; int ir = sidx[tid + off];
            float vl = sval[tid];       int il = sidx[tid];
            if (vr > vl || (vr == vl && ir < il)) { sval[tid] = vr; sidx[tid] = ir; }
        }
        __syncthreads();
    }

    // layer 1: 256 -> 32
    if (tid < 32) {
        float acc = b1[tid];
        const float* wrow = W1 + tid * 256;
        for (int k = 0; k < 256; ++k) acc += sh[k] * wrow[k];
        h1[tid] = fmaxf(acc, 0.0f);
    }
    // threshold value (exact: integer counts, fp32 compare identical to ref)
    if (tid == 0) {
        float maxv = sval[0];
        int   cb   = sidx[0];
        float ch   = maxv * 0.05f;
        int res = 0;
        for (int i = cb; i < BINS; ++i) {
            if (sh[i] <= ch) { res = i; break; }   // first false of cond
        }
        value_out[b] = (float)res * (1.0f / 256.0f);
    }
    __syncthreads();

    // layer 2: 32 -> 64
    if (tid < 64) {
        float acc = b2[tid];
        const float* wrow = W2 + tid * 32;
        for (int k = 0; k < 32; ++k) acc += h1[k] * wrow[k];
        h2[tid] = fmaxf(acc, 0.0f);
    }
    __syncthreads();

    // layer 3: 64 -> 128
    if (tid < 128) {
        float acc = b3[tid];
        const float* wrow = W3 + tid * 64;
        for (int k = 0; k < 64; ++k) acc += h2[k] * wrow[k];
        h3[tid] = fmaxf(acc, 0.0f);
    }
    __syncthreads();

    // layer 4: 128 -> 1
    if (tid == 0) {
        float acc = b4[0];
        for (int k = 0; k < 128; ++k) acc += h3[k] * W4[k];
        wout[b] = acc;
    }
}

// ---------------------------------------------------------------- scale
// 64 blocks per batch; each block covers 4096 floats (256 thr * 4 float4).
__global__ __launch_bounds__(256) void scale_kernel(const float* __restrict__ x,
                                                    const float* __restrict__ wv,
                                                    float* __restrict__ out) {
    const int   batch = blockIdx.x >> 6;
    const float w     = wv[batch];
    const size_t base = (size_t)blockIdx.x * 4096;
    const float4* xp  = (const float4*)(x + base);
    float4*       op  = (float4*)(out + base);
    #pragma unroll
    for (int it = 0; it < 4; ++it) {
        float4 v = xp[it * 256 + threadIdx.x];
        v.x *= w; v.y *= w; v.z *= w; v.w *= w;
        op[it * 256 + threadIdx.x] = v;
    }
}

// ---------------------------------------------------------------- launch
extern "C" void kernel_launch(void* const* d_in, const int* in_sizes, int n_in,
                              void* d_out, int out_size, void* d_ws, size_t ws_size,
                              hipStream_t stream) {
    const float* x  = (const float*)d_in[0];
    const float* W1 = (const float*)d_in[1];
    const float* b1 = (const float*)d_in[2];
    const float* W2 = (const float*)d_in[3];
    const float* b2 = (const float*)d_in[4];
    const float* W3 = (const float*)d_in[5];
    const float* b3 = (const float*)d_in[6];
    const float* W4 = (const float*)d_in[7];
    const float* b4 = (const float*)d_in[8];

    float* out = (float*)d_out;
    float* value_out = out + (size_t)NBATCH * NPB;   // outputs concat: [out | value]

    unsigned int* gh = (unsigned int*)d_ws;                         // 128*256 u32
    float* wv = (float*)((char*)d_ws + NBATCH * BINS * sizeof(unsigned int));

    zero_hist <<<NBATCH,            256, 0, stream>>>(gh);
    hist_kernel<<<NBATCH * 32,      256, 0, stream>>>(x, gh);
    mlp_kernel <<<NBATCH,           256, 0, stream>>>(gh, W1, b1, W2, b2, W3, b3,
                                                      W4, b4, wv, value_out);
    scale_kernel<<<NBATCH * 64,     256, 0, stream>>>(x, wv, out);
}

// Round 3
// 279.384 us; speedup vs baseline: 1.0431x; 1.0431x over previous
//
#include <hip/hip_runtime.h>

#define NBATCH 128
#define NPB    262144      // 1*512*512 elements per batch
#define BINS   256
#define HCHUNK 8           // partial histograms per batch

// ---------------------------------------------------------------- histogram
// grid = 128*8 blocks; each block histograms 32768 elems (256 thr * 32 float4)
// into LDS sub-histograms, then writes a PRIVATE 256-bin partial to ws.
// No global atomics, no pre-zero kernel.
__global__ __launch_bounds__(256) void hist_kernel(const float* __restrict__ x,
                                                   unsigned int* __restrict__ ph) {
    __shared__ unsigned int lh[4][BINS];   // per-wave sub-histograms
    const int tid = threadIdx.x;
    const int wid = tid >> 6;
    #pragma unroll
    for (int i = 0; i < 4; ++i) ((unsigned int*)lh)[i * 256 + tid] = 0u;
    __syncthreads();

    const int batch = blockIdx.x >> 3;
    const int chunk = blockIdx.x & 7;
    const float4* xp = (const float4*)(x + (size_t)batch * NPB + (size_t)chunk * 32768);
    unsigned int* mh = lh[wid];

    #pragma unroll
    for (int it = 0; it < 32; ++it) {
        float4 v = xp[it * 256 + tid];
        float vals[4] = {v.x, v.y, v.z, v.w};
        #pragma unroll
        for (int j = 0; j < 4; ++j) {
            float f = vals[j];
            // exact replica of jnp: clip(floor(f*256), 0, 255); ignore out-of-[0,1]
            int bin = (int)floorf(f * 256.0f);
            bin = bin < 0 ? 0 : (bin > 255 ? 255 : bin);
            if (f >= 0.0f && f <= 1.0f) atomicAdd(&mh[bin], 1u);
        }
    }
    __syncthreads();
    unsigned int s = lh[0][tid] + lh[1][tid] + lh[2][tid] + lh[3][tid];
    ph[(size_t)blockIdx.x * BINS + tid] = s;     // [batch][chunk][256]
}

// ---------------------------------------------------------------- mlp+value
__global__ __launch_bounds__(256) void mlp_kernel(const unsigned int* __restrict__ ph,
    const float* __restrict__ W1, const float* __restrict__ b1,
    const float* __restrict__ W2, const float* __restrict__ b2,
    const float* __restrict__ W3, const float* __restrict__ b3,
    const float* __restrict__ W4, const float* __restrict__ b4,
    float* __restrict__ wout, float* __restrict__ value_out) {

    __shared__ float sh[BINS];
    __shared__ float sval[BINS];
    __shared__ int   sidx[BINS];
    __shared__ unsigned long long masks[4];
    __shared__ float h1[32], h2[64], h3[128];

    const int tid = threadIdx.x;
    const int b   = blockIdx.x;

    // sum the 8 per-chunk partials (exact integer sum)
    unsigned int acc_u = 0;
    #pragma unroll
    for (int c = 0; c < HCHUNK; ++c)
        acc_u += ph[((size_t)b * HCHUNK + c) * BINS + tid];
    float hv = (float)acc_u;
    sh[tid]   = hv;
    sval[tid] = hv;
    sidx[tid] = tid;
    __syncthreads();

    // max + FIRST argmax (jnp.argmax tie-break: lowest index)
    for (int off = 128; off > 0; off >>= 1) {
        if (tid < off) {
            float vr = sval[tid + off]; int ir = sidx[tid + off];
            float vl = sval[tid];       int il = sidx[tid];
            if (vr > vl || (vr == vl && ir < il)) { sval[tid] = vr; sidx[tid] = ir; }
        }
        __syncthreads();
    }
    const float maxv = sval[0];
    const int   cb   = sidx[0];
    const float ch   = maxv * 0.05f;

    // ballot-parallel threshold: first index where cond is false, else 0
    {
        bool notcond = !((tid < cb) || (sh[tid] > ch));
        unsigned long long m = __ballot(notcond);
        if ((tid & 63) == 0) masks[tid >> 6] = m;
    }
    __syncthreads();
    if (tid == 0) {
        int res = 0;
        #pragma unroll
        for (int w = 0; w < 4; ++w) {
            unsigned long long mm = masks[w];
            if (mm) { res = w * 64 + __ffsll(mm) - 1; break; }
        }
        value_out[b] = (float)res * (1.0f / 256.0f);
    }

    // layer 1: 256 -> 32  (same serial fp order as the passing run)
    if (tid < 32) {
        float acc = b1[tid];
        const float* wrow = W1 + tid * 256;
        for (int k = 0; k < 256; ++k) acc += sh[k] * wrow[k];
        h1[tid] = fmaxf(acc, 0.0f);
    }
    __syncthreads();

    // layer 2: 32 -> 64
    if (tid < 64) {
        float acc = b2[tid];
        const float* wrow = W2 + tid * 32;
        for (int k = 0; k < 32; ++k) acc += h1[k] * wrow[k];
        h2[tid] = fmaxf(acc, 0.0f);
    }
    __syncthreads();

    // layer 3: 64 -> 128
    if (tid < 128) {
        float acc = b3[tid];
        const float* wrow = W3 + tid * 64;
        for (int k = 0; k < 64; ++k) acc += h2[k] * wrow[k];
        h3[tid] = fmaxf(acc, 0.0f);
    }
    __syncthreads();

    // layer 4: 128 -> 1
    if (tid == 0) {
        float acc = b4[0];
        for (int k = 0; k < 128; ++k) acc += h3[k] * W4[k];
        wout[b] = acc;
    }
}

// ---------------------------------------------------------------- scale
// grid 2048 blocks; each covers 16384 floats (256 thr * 16 float4).
__global__ __launch_bounds__(256) void scale_kernel(const float* __restrict__ x,
                                                    const float* __restrict__ wv,
                                                    float* __restrict__ out) {
    const int   tid   = threadIdx.x;
    const int   batch = blockIdx.x >> 4;           // 16 blocks per batch
    const float w     = wv[batch];
    const float4* xp  = (const float4*)x   + (size_t)blockIdx.x * 4096;
    float4*       op  = (float4*)out       + (size_t)blockIdx.x * 4096;
    #pragma unroll
    for (int it = 0; it < 16; ++it) {
        float4 v = xp[it * 256 + tid];
        v.x *= w; v.y *= w; v.z *= w; v.w *= w;
        op[it * 256 + tid] = v;
    }
}

// ---------------------------------------------------------------- launch
extern "C" void kernel_launch(void* const* d_in, const int* in_sizes, int n_in,
                              void* d_out, int out_size, void* d_ws, size_t ws_size,
                              hipStream_t stream) {
    const float* x  = (const float*)d_in[0];
    const float* W1 = (const float*)d_in[1];
    const float* b1 = (const float*)d_in[2];
    const float* W2 = (const float*)d_in[3];
    const float* b2 = (const float*)d_in[4];
    const float* W3 = (const float*)d_in[5];
    const float* b3 = (const float*)d_in[6];
    const float* W4 = (const float*)d_in[7];
    const float* b4 = (const float*)d_in[8];

    float* out = (float*)d_out;
    float* value_out = out + (size_t)NBATCH * NPB;   // outputs concat: [out | value]

    unsigned int* ph = (unsigned int*)d_ws;          // 128*8*256 u32 = 1 MB
    float* wv = (float*)((char*)d_ws + (size_t)NBATCH * HCHUNK * BINS * sizeof(unsigned int));

    hist_kernel <<<NBATCH * HCHUNK, 256, 0, stream>>>(x, ph);
    mlp_kernel  <<<NBATCH,          256, 0, stream>>>(ph, W1, b1, W2, b2, W3, b3,
                                                      W4, b4, wv, value_out);
    scale_kernel<<<2048,            256, 0, stream>>>(x, wv, out);
}